// Round 9
// baseline (332.416 us; speedup 1.0000x reference)
//
#include <hip/hip_runtime.h>
#include <hip/hip_bf16.h>

#define T_TOK 8192
#define NEXP 8
#define DMODEL 1024
#define DHID 4096

typedef __bf16 bf16x8_t __attribute__((ext_vector_type(8)));
typedef float f32x4_t __attribute__((ext_vector_type(4)));

#define AS1 __attribute__((address_space(1)))
#define AS3 __attribute__((address_space(3)))

__device__ __forceinline__ unsigned short f2bf(float f) {
    union { float f; unsigned int u; } x;
    x.f = f;
    unsigned int r = x.u + 0x7fffu + ((x.u >> 16) & 1u);  // RNE
    return (unsigned short)(r >> 16);
}

__global__ __launch_bounds__(256) void k_cvt(const float4* __restrict__ in,
                                             ushort4* __restrict__ out, int n4) {
    int i = blockIdx.x * 256 + threadIdx.x;
    if (i >= n4) return;
    float4 v = in[i];
    ushort4 o;
    o.x = f2bf(v.x); o.y = f2bf(v.y); o.z = f2bf(v.z); o.w = f2bf(v.w);
    out[i] = o;
}

__global__ __launch_bounds__(256) void k_transpose_cvt(const float* __restrict__ in,
                                                       unsigned short* __restrict__ out,
                                                       int K, int N) {
    __shared__ float tile[32][33];
    int e = blockIdx.z;
    int k0 = blockIdx.y << 5;
    int n0 = blockIdx.x << 5;
    int t = threadIdx.x;
    int r = t >> 3;
    int c = (t & 7) << 2;
    const float* src = in + ((size_t)e * K + (k0 + r)) * N + n0 + c;
    float4 v = *(const float4*)src;
    tile[r][c + 0] = v.x; tile[r][c + 1] = v.y; tile[r][c + 2] = v.z; tile[r][c + 3] = v.w;
    __syncthreads();
    ushort4 o;
    o.x = f2bf(tile[c + 0][r]);
    o.y = f2bf(tile[c + 1][r]);
    o.z = f2bf(tile[c + 2][r]);
    o.w = f2bf(tile[c + 3][r]);
    unsigned short* dst = out + ((size_t)e * N + (n0 + r)) * K + k0 + c;
    *(ushort4*)dst = o;
}

// ---------------------------------------------------------------------------
// Grouped GEMM, BMx128 tile, BK=64, per-wave 64x64 (waves = BM/32, threads =
// BM*2). r8's proven inner structure (single LDS buffer, stage -> sync ->
// compute -> sync, strength-reduced addressing, XOR swizzle, XCD-swizzled
// blockIdx). Round 9 experiment: GEMM1 at BM=256 cuts cache-level read
// traffic from 1.05 GB -> 768 MB (theory: kernels are L2/L3-BW-bound at
// ~8.7 TB/s); GEMM2 stays BM=128 as the control.
// ---------------------------------------------------------------------------
template<int K, int N, int BM, bool GELU>
__global__ void k_gemm(const unsigned short* __restrict__ A,
                       const unsigned short* __restrict__ Bt,
                       void* __restrict__ C) {
    constexpr int NTN = N / 128;
    constexpr int NMT = T_TOK / BM;
    constexpr int NWG = NMT * NTN;
    constexpr int T = BM * 2;            // threads (512 for BM=256, 256 for BM=128)
    constexpr int ROWS = T / 8;          // rows staged per global_load_lds issue
    constexpr int NIA = BM / ROWS;       // A staging issues
    constexpr int NIB = 128 / ROWS;      // B staging issues

    __shared__ __align__(16) char LDS[BM * 128 + 16384];   // A: [0,BM*128), B after

    const int tid = threadIdx.x;
    const int lane = tid & 63;
    const int wid = tid >> 6;
    const int wr = wid >> 1;             // 0..BM/64-1
    const int wc = wid & 1;              // 0..1

    // bijective XCD swizzle (NWG % 8 == 0 for both GEMMs)
    const int bid = blockIdx.x;
    const int s = (bid & 7) * (NWG / 8) + (bid >> 3);
    const int nt = s % NTN;
    const int mt = s / NTN;
    const int e = (mt * BM) >> 10;       // 1024 tokens per expert

    const char* Aptr = (const char*)(A + (size_t)mt * BM * K);
    const char* Bptr = (const char*)(Bt + ((size_t)e * N + (size_t)nt * 128) * K);

    // K-tile-invariant staging offset: thread stages 16B slot (tid&7) of
    // row (tid>>3) within each ROWS-row group; source col inverse-swizzled.
    const int goff = (tid >> 3) * (K * 2) + ((((tid & 7) << 4)) ^ ((((tid >> 3)) & 7) << 4));

    // K-tile-invariant fragment read bases; frag row = wr*64+frag*16+(lane&15)
    // -> row&7 == lane&7; byte = pre[kk] + frag*2048.
    int preA[2], preB[2];
    #pragma unroll
    for (int kk = 0; kk < 2; ++kk) {
        const int sw = ((kk * 64) + ((lane >> 4) << 4)) ^ ((lane & 7) << 4);
        preA[kk] = wr * 8192 + (lane & 15) * 128 + sw;
        preB[kk] = BM * 128 + wc * 8192 + (lane & 15) * 128 + sw;
    }

    f32x4_t acc[4][4] = {};

    for (int kt = 0; kt < K / 64; ++kt) {
        #pragma unroll
        for (int i = 0; i < NIA; ++i)
            __builtin_amdgcn_global_load_lds(
                (const AS1 void*)(Aptr + (goff + i * (ROWS * K * 2))),
                (AS3 void*)(LDS + i * (ROWS * 128) + tid * 16), 16, 0, 0);
        #pragma unroll
        for (int i = 0; i < NIB; ++i)
            __builtin_amdgcn_global_load_lds(
                (const AS1 void*)(Bptr + (goff + i * (ROWS * K * 2))),
                (AS3 void*)(LDS + BM * 128 + i * (ROWS * 128) + tid * 16), 16, 0, 0);
        Aptr += 128;   // uniform scalar bump: next BK=64 slice
        Bptr += 128;
        __syncthreads();   // vmcnt(0) drain + barrier: tile published
        #pragma unroll
        for (int kk = 0; kk < 2; ++kk) {
            bf16x8_t af[4], bv[4];
            #pragma unroll
            for (int m = 0; m < 4; ++m)
                af[m] = *(const bf16x8_t*)(LDS + preA[kk] + m * 2048);
            #pragma unroll
            for (int n = 0; n < 4; ++n)
                bv[n] = *(const bf16x8_t*)(LDS + preB[kk] + n * 2048);
            #pragma unroll
            for (int m = 0; m < 4; ++m)
                #pragma unroll
                for (int n = 0; n < 4; ++n)
                    acc[m][n] = __builtin_amdgcn_mfma_f32_16x16x32_bf16(
                        af[m], bv[n], acc[m][n], 0, 0, 0);
        }
        __syncthreads();   // ds_reads complete before next tile overwrites
    }

    // C/D layout: col = lane&15, row = (lane>>4)*4 + j  [m89/m91]
    const int r0 = mt * BM + wr * 64 + ((lane >> 4) << 2);
    const int c0 = nt * 128 + wc * 64 + (lane & 15);
    if (GELU) {
        unsigned short* Co = (unsigned short*)C;
        #pragma unroll
        for (int m = 0; m < 4; ++m)
            #pragma unroll
            for (int n = 0; n < 4; ++n)
                #pragma unroll
                for (int j = 0; j < 4; ++j) {
                    float x = acc[m][n][j];
                    float u = 1.5957691216057308f * (x + 0.044715f * x * x * x);
                    float g = x / (1.f + __expf(-u));
                    Co[(size_t)(r0 + m * 16 + j) * N + (c0 + n * 16)] = f2bf(g);
                }
    } else {
        float* Co = (float*)C;
        #pragma unroll
        for (int m = 0; m < 4; ++m)
            #pragma unroll
            for (int n = 0; n < 4; ++n)
                #pragma unroll
                for (int j = 0; j < 4; ++j)
                    Co[(size_t)(r0 + m * 16 + j) * N + (c0 + n * 16)] = acc[m][n][j];
    }
}

extern "C" void kernel_launch(void* const* d_in, const int* in_sizes, int n_in,
                              void* d_out, int out_size, void* d_ws, size_t ws_size,
                              hipStream_t stream) {
    (void)in_sizes; (void)n_in; (void)out_size; (void)ws_size;
    const float* inp = (const float*)d_in[0];
    const float* w1  = (const float*)d_in[1];
    const float* w2  = (const float*)d_in[2];
    float* out = (float*)d_out;

    char* ws = (char*)d_ws;
    unsigned short* wbuf = (unsigned short*)ws;                                 // 64 MB (w1t, then w2t)
    unsigned short* xb   = (unsigned short*)(ws + (size_t)64 * 1024 * 1024);    // 16 MB
    unsigned short* hbuf = (unsigned short*)(ws + (size_t)80 * 1024 * 1024);    // 64 MB

    // 1) x: f32 -> bf16
    k_cvt<<<dim3((T_TOK * DMODEL / 4) / 256), 256, 0, stream>>>(
        (const float4*)inp, (ushort4*)xb, T_TOK * DMODEL / 4);

    // 2) w1 [E][D][H] -> w1t [E][H][D] bf16
    k_transpose_cvt<<<dim3(DHID / 32, DMODEL / 32, NEXP), 256, 0, stream>>>(
        w1, wbuf, DMODEL, DHID);

    // 3) h = gelu(x @ w1[e])   — TREATMENT: 256x128 tile, 1024 blocks, 3/CU
    k_gemm<DMODEL, DHID, 256, true>
        <<<dim3((T_TOK / 256) * (DHID / 128)), 512, 0, stream>>>(xb, wbuf, hbuf);

    // 4) w2 [E][H][D] -> w2t [E][D][H] bf16 (reuse wbuf)
    k_transpose_cvt<<<dim3(DMODEL / 32, DHID / 32, NEXP), 256, 0, stream>>>(
        w2, wbuf, DHID, DMODEL);

    // 5) out = h @ w2[e]   — CONTROL: 128x128 tile, 512 blocks (r8-identical)
    k_gemm<DHID, DMODEL, 128, false>
        <<<dim3((T_TOK / 128) * (DMODEL / 128)), 256, 0, stream>>>(hbuf, wbuf, out);
}

// Round 10
// 266.177 us; speedup vs baseline: 1.2489x; 1.2489x over previous
//
#include <hip/hip_runtime.h>
#include <hip/hip_bf16.h>

#define T_TOK 8192
#define NEXP 8
#define DMODEL 1024
#define DHID 4096

typedef __bf16 bf16x8_t __attribute__((ext_vector_type(8)));
typedef float f32x4_t __attribute__((ext_vector_type(4)));

#define AS1 __attribute__((address_space(1)))
#define AS3 __attribute__((address_space(3)))

__device__ __forceinline__ unsigned short f2bf(float f) {
    union { float f; unsigned int u; } x;
    x.f = f;
    unsigned int r = x.u + 0x7fffu + ((x.u >> 16) & 1u);  // RNE
    return (unsigned short)(r >> 16);
}

__global__ __launch_bounds__(256) void k_cvt(const float4* __restrict__ in,
                                             ushort4* __restrict__ out, int n4) {
    int i = blockIdx.x * 256 + threadIdx.x;
    if (i >= n4) return;
    float4 v = in[i];
    ushort4 o;
    o.x = f2bf(v.x); o.y = f2bf(v.y); o.z = f2bf(v.z); o.w = f2bf(v.w);
    out[i] = o;
}

__global__ __launch_bounds__(256) void k_transpose_cvt(const float* __restrict__ in,
                                                       unsigned short* __restrict__ out,
                                                       int K, int N) {
    __shared__ float tile[32][33];
    int e = blockIdx.z;
    int k0 = blockIdx.y << 5;
    int n0 = blockIdx.x << 5;
    int t = threadIdx.x;
    int r = t >> 3;
    int c = (t & 7) << 2;
    const float* src = in + ((size_t)e * K + (k0 + r)) * N + n0 + c;
    float4 v = *(const float4*)src;
    tile[r][c + 0] = v.x; tile[r][c + 1] = v.y; tile[r][c + 2] = v.z; tile[r][c + 3] = v.w;
    __syncthreads();
    ushort4 o;
    o.x = f2bf(tile[c + 0][r]);
    o.y = f2bf(tile[c + 1][r]);
    o.z = f2bf(tile[c + 2][r]);
    o.w = f2bf(tile[c + 3][r]);
    unsigned short* dst = out + ((size_t)e * N + (n0 + r)) * K + k0 + c;
    *(ushort4*)dst = o;
}

// ---------------------------------------------------------------------------
// Grouped GEMM, BMx128 tile, BK=64, per-wave 64x64 (waves = BM/32, threads =
// BM*2). r8's proven inner structure (single LDS buffer, stage -> sync ->
// compute -> sync, strength-reduced addressing, XOR swizzle, XCD-swizzled
// blockIdx). Round 10 = round 9 DE-CONFOUNDED: __launch_bounds__(BM*2)
// restored (r9 accidentally dropped it -> compiler assumed 1024-thr blocks
// -> VGPR capped at 64 -> r7-style register starvation in BOTH arms).
// Experiment unchanged: GEMM1 BM=256 (treatment, -27% cache-level traffic),
// GEMM2 BM=128 (control, r8-identical config).
// ---------------------------------------------------------------------------
template<int K, int N, int BM, bool GELU>
__global__ __launch_bounds__(BM * 2) void k_gemm(const unsigned short* __restrict__ A,
                                                 const unsigned short* __restrict__ Bt,
                                                 void* __restrict__ C) {
    constexpr int NTN = N / 128;
    constexpr int NMT = T_TOK / BM;
    constexpr int NWG = NMT * NTN;
    constexpr int T = BM * 2;            // threads (512 for BM=256, 256 for BM=128)
    constexpr int ROWS = T / 8;          // rows staged per global_load_lds issue
    constexpr int NIA = BM / ROWS;       // A staging issues
    constexpr int NIB = 128 / ROWS;      // B staging issues

    __shared__ __align__(16) char LDS[BM * 128 + 16384];   // A: [0,BM*128), B after

    const int tid = threadIdx.x;
    const int lane = tid & 63;
    const int wid = tid >> 6;
    const int wr = wid >> 1;             // 0..BM/64-1
    const int wc = wid & 1;              // 0..1

    // bijective XCD swizzle (NWG % 8 == 0 for both GEMMs)
    const int bid = blockIdx.x;
    const int s = (bid & 7) * (NWG / 8) + (bid >> 3);
    const int nt = s % NTN;
    const int mt = s / NTN;
    const int e = (mt * BM) >> 10;       // 1024 tokens per expert

    const char* Aptr = (const char*)(A + (size_t)mt * BM * K);
    const char* Bptr = (const char*)(Bt + ((size_t)e * N + (size_t)nt * 128) * K);

    // K-tile-invariant staging offset: thread stages 16B slot (tid&7) of
    // row (tid>>3) within each ROWS-row group; source col inverse-swizzled.
    const int goff = (tid >> 3) * (K * 2) + ((((tid & 7) << 4)) ^ ((((tid >> 3)) & 7) << 4));

    // K-tile-invariant fragment read bases; frag row = wr*64+frag*16+(lane&15)
    // -> row&7 == lane&7; byte = pre[kk] + frag*2048.
    int preA[2], preB[2];
    #pragma unroll
    for (int kk = 0; kk < 2; ++kk) {
        const int sw = ((kk * 64) + ((lane >> 4) << 4)) ^ ((lane & 7) << 4);
        preA[kk] = wr * 8192 + (lane & 15) * 128 + sw;
        preB[kk] = BM * 128 + wc * 8192 + (lane & 15) * 128 + sw;
    }

    f32x4_t acc[4][4] = {};

    for (int kt = 0; kt < K / 64; ++kt) {
        #pragma unroll
        for (int i = 0; i < NIA; ++i)
            __builtin_amdgcn_global_load_lds(
                (const AS1 void*)(Aptr + (goff + i * (ROWS * K * 2))),
                (AS3 void*)(LDS + i * (ROWS * 128) + tid * 16), 16, 0, 0);
        #pragma unroll
        for (int i = 0; i < NIB; ++i)
            __builtin_amdgcn_global_load_lds(
                (const AS1 void*)(Bptr + (goff + i * (ROWS * K * 2))),
                (AS3 void*)(LDS + BM * 128 + i * (ROWS * 128) + tid * 16), 16, 0, 0);
        Aptr += 128;   // uniform scalar bump: next BK=64 slice
        Bptr += 128;
        __syncthreads();   // vmcnt(0) drain + barrier: tile published
        #pragma unroll
        for (int kk = 0; kk < 2; ++kk) {
            bf16x8_t af[4], bv[4];
            #pragma unroll
            for (int m = 0; m < 4; ++m)
                af[m] = *(const bf16x8_t*)(LDS + preA[kk] + m * 2048);
            #pragma unroll
            for (int n = 0; n < 4; ++n)
                bv[n] = *(const bf16x8_t*)(LDS + preB[kk] + n * 2048);
            #pragma unroll
            for (int m = 0; m < 4; ++m)
                #pragma unroll
                for (int n = 0; n < 4; ++n)
                    acc[m][n] = __builtin_amdgcn_mfma_f32_16x16x32_bf16(
                        af[m], bv[n], acc[m][n], 0, 0, 0);
        }
        __syncthreads();   // ds_reads complete before next tile overwrites
    }

    // C/D layout: col = lane&15, row = (lane>>4)*4 + j  [m89/m91]
    const int r0 = mt * BM + wr * 64 + ((lane >> 4) << 2);
    const int c0 = nt * 128 + wc * 64 + (lane & 15);
    if (GELU) {
        unsigned short* Co = (unsigned short*)C;
        #pragma unroll
        for (int m = 0; m < 4; ++m)
            #pragma unroll
            for (int n = 0; n < 4; ++n)
                #pragma unroll
                for (int j = 0; j < 4; ++j) {
                    float x = acc[m][n][j];
                    float u = 1.5957691216057308f * (x + 0.044715f * x * x * x);
                    float g = x / (1.f + __expf(-u));
                    Co[(size_t)(r0 + m * 16 + j) * N + (c0 + n * 16)] = f2bf(g);
                }
    } else {
        float* Co = (float*)C;
        #pragma unroll
        for (int m = 0; m < 4; ++m)
            #pragma unroll
            for (int n = 0; n < 4; ++n)
                #pragma unroll
                for (int j = 0; j < 4; ++j)
                    Co[(size_t)(r0 + m * 16 + j) * N + (c0 + n * 16)] = acc[m][n][j];
    }
}

extern "C" void kernel_launch(void* const* d_in, const int* in_sizes, int n_in,
                              void* d_out, int out_size, void* d_ws, size_t ws_size,
                              hipStream_t stream) {
    (void)in_sizes; (void)n_in; (void)out_size; (void)ws_size;
    const float* inp = (const float*)d_in[0];
    const float* w1  = (const float*)d_in[1];
    const float* w2  = (const float*)d_in[2];
    float* out = (float*)d_out;

    char* ws = (char*)d_ws;
    unsigned short* wbuf = (unsigned short*)ws;                                 // 64 MB (w1t, then w2t)
    unsigned short* xb   = (unsigned short*)(ws + (size_t)64 * 1024 * 1024);    // 16 MB
    unsigned short* hbuf = (unsigned short*)(ws + (size_t)80 * 1024 * 1024);    // 64 MB

    // 1) x: f32 -> bf16
    k_cvt<<<dim3((T_TOK * DMODEL / 4) / 256), 256, 0, stream>>>(
        (const float4*)inp, (ushort4*)xb, T_TOK * DMODEL / 4);

    // 2) w1 [E][D][H] -> w1t [E][H][D] bf16
    k_transpose_cvt<<<dim3(DHID / 32, DMODEL / 32, NEXP), 256, 0, stream>>>(
        w1, wbuf, DMODEL, DHID);

    // 3) h = gelu(x @ w1[e])   — TREATMENT: 256x128 tile, 1024 blocks
    k_gemm<DMODEL, DHID, 256, true>
        <<<dim3((T_TOK / 256) * (DHID / 128)), 512, 0, stream>>>(xb, wbuf, hbuf);

    // 4) w2 [E][H][D] -> w2t [E][D][H] bf16 (reuse wbuf)
    k_transpose_cvt<<<dim3(DMODEL / 32, DHID / 32, NEXP), 256, 0, stream>>>(
        w2, wbuf, DHID, DMODEL);

    // 5) out = h @ w2[e]   — CONTROL: 128x128 tile, 512 blocks (r8-identical)
    k_gemm<DHID, DMODEL, 128, false>
        <<<dim3((T_TOK / 128) * (DMODEL / 128)), 256, 0, stream>>>(hbuf, wbuf, out);
}